// Round 2
// baseline (6778.184 us; speedup 1.0000x reference)
//
#include <hip/hip_runtime.h>
#include <hip/hip_bf16.h>
#include <math.h>

// Problem constants
#define Bq 4
#define Sq 1024
#define Eq 1024
#define Hq 16
#define Dq 64

// ---------------------------------------------------------------------------
// GEMM: C[M,N] = (A[M,K] @ Bw[N,K]^T + bias[N]) * scale   (torch Linear style)
// 64x64 tile, BK=16, 256 threads, 4x4 register micro-tile. fp32.
// ---------------------------------------------------------------------------
#define TILE 64
#define BK 16
#define APAD 68  // 64 + 4 pad: keeps 16B alignment for b128 reads, kills bank conflicts

__global__ __launch_bounds__(256) void gemm_bt(
    const float* __restrict__ A,    // [M,K]
    const float* __restrict__ Bw,   // [N,K]
    const float* __restrict__ bias, // [N]
    float* __restrict__ C,          // [M,N]
    int M, int N, int K, float scale)
{
    __shared__ float As[BK][APAD];
    __shared__ float Bs[BK][APAD];

    const int bm = blockIdx.y * TILE;
    const int bn = blockIdx.x * TILE;
    const int t  = threadIdx.x;
    const int tn = t & 15;   // 0..15 -> column group
    const int tm = t >> 4;   // 0..15 -> row group

    float acc[4][4] = {};

    const int lk = t & 15;   // k within tile for loads
    const int lm = t >> 4;   // 0..15

    for (int k0 = 0; k0 < K; k0 += BK) {
#pragma unroll
        for (int r = 0; r < 4; r++) {
            As[lk][lm + 16 * r] = A[(size_t)(bm + lm + 16 * r) * K + k0 + lk];
            Bs[lk][lm + 16 * r] = Bw[(size_t)(bn + lm + 16 * r) * K + k0 + lk];
        }
        __syncthreads();
#pragma unroll
        for (int kk = 0; kk < BK; kk++) {
            float a[4], b[4];
#pragma unroll
            for (int i = 0; i < 4; i++) a[i] = As[kk][tm * 4 + i];
#pragma unroll
            for (int j = 0; j < 4; j++) b[j] = Bs[kk][tn * 4 + j];
#pragma unroll
            for (int i = 0; i < 4; i++)
#pragma unroll
                for (int j = 0; j < 4; j++)
                    acc[i][j] += a[i] * b[j];
        }
        __syncthreads();
    }

    const float4 bb = *(const float4*)(bias + bn + tn * 4);
#pragma unroll
    for (int i = 0; i < 4; i++) {
        const int row = bm + tm * 4 + i;
        float4 o;
        o.x = (acc[i][0] + bb.x) * scale;
        o.y = (acc[i][1] + bb.y) * scale;
        o.z = (acc[i][2] + bb.z) * scale;
        o.w = (acc[i][3] + bb.w) * scale;
        *(float4*)(C + (size_t)row * N + bn + tn * 4) = o;
    }
}

// ---------------------------------------------------------------------------
// Scores + softmax: one block per (b,h, 16-q group). 256 threads.
// Thread t owns k-columns {t, t+256, t+512, t+768} for ALL 16 q rows.
// __launch_bounds__(256, 2): 256-VGPR cap so sc[4][16] + pipeline regs live
// in registers (80-VGPR default spilled to scratch -> latency-bound, r1).
// ---------------------------------------------------------------------------
#define QB 16

__global__ __launch_bounds__(256, 2) void attn_scores(
    const float* __restrict__ Q,     // [B*S, E] (pre-scaled)
    const float* __restrict__ Km,    // [B*S, E]
    const float* __restrict__ bias,  // [B,H,S,S]
    const int*   __restrict__ mask,  // [B,S]
    float* __restrict__ W)           // [B,H,S,S]
{
    const int bid = blockIdx.x;
    const int qc = bid & (Sq / QB - 1);       // 0..63
    const int h  = (bid >> 6) & (Hq - 1);
    const int b  = bid >> 10;
    const int q0 = qc * QB;

    __shared__ __align__(16) float qs[QB][Dq];
    __shared__ float redm[QB][4];
    __shared__ float reds[QB][4];

    const int t = threadIdx.x;

    // load 16 q rows (16*64 floats = 256 float4s, one per thread)
    {
        const int qq = t >> 4;   // 16 float4 per row
        const int c4 = t & 15;
        ((float4*)qs[qq])[c4] =
            *(const float4*)(Q + ((size_t)(b * Sq + q0 + qq)) * Eq + h * Dq + c4 * 4);
    }
    __syncthreads();

    const float* Kbase = Km + (size_t)b * Sq * Eq + h * Dq;

    float sc[4][QB];
#pragma unroll
    for (int j = 0; j < 4; j++)
#pragma unroll
        for (int qq = 0; qq < QB; qq++) sc[j][qq] = 0.f;

    // software-pipelined over c: load kv for c+1 while computing c
    float4 kv[4];
#pragma unroll
    for (int j = 0; j < 4; j++)
        kv[j] = *(const float4*)(Kbase + (size_t)(t + 256 * j) * Eq);

#pragma unroll
    for (int c = 0; c < Dq / 4; c++) {
        float4 kn[4];
        if (c + 1 < Dq / 4) {
#pragma unroll
            for (int j = 0; j < 4; j++)
                kn[j] = *(const float4*)(Kbase + (size_t)(t + 256 * j) * Eq + (c + 1) * 4);
        }
#pragma unroll
        for (int qh = 0; qh < 4; qh++) {
            float4 qr[4];
#pragma unroll
            for (int u = 0; u < 4; u++) qr[u] = ((const float4*)qs[qh * 4 + u])[c];
#pragma unroll
            for (int j = 0; j < 4; j++)
#pragma unroll
                for (int u = 0; u < 4; u++)
                    sc[j][qh * 4 + u] += kv[j].x * qr[u].x + kv[j].y * qr[u].y
                                       + kv[j].z * qr[u].z + kv[j].w * qr[u].w;
        }
#pragma unroll
        for (int j = 0; j < 4; j++) kv[j] = kn[j];
    }

    // bias + mask + per-thread max
    const int* mrow = mask + b * Sq;
    const float* biasBase = bias + ((size_t)(b * Hq + h) * Sq + q0) * Sq;

    float mx[QB];
#pragma unroll
    for (int qq = 0; qq < QB; qq++) mx[qq] = -INFINITY;

#pragma unroll
    for (int j = 0; j < 4; j++) {
        const int k = t + 256 * j;
        const bool msk = (mrow[k] != 0);
#pragma unroll
        for (int qq = 0; qq < QB; qq++) {
            float d = msk ? -INFINITY : (sc[j][qq] + biasBase[(size_t)qq * Sq + k]);
            sc[j][qq] = d;
            mx[qq] = fmaxf(mx[qq], d);
        }
    }

    const int lane = t & 63;
    const int wid  = t >> 6;

    // wave-level max reduce, then cross-wave (4 waves)
#pragma unroll
    for (int off = 32; off > 0; off >>= 1)
#pragma unroll
        for (int qq = 0; qq < QB; qq++)
            mx[qq] = fmaxf(mx[qq], __shfl_xor(mx[qq], off));
    if (lane == 0) {
#pragma unroll
        for (int qq = 0; qq < QB; qq++) redm[qq][wid] = mx[qq];
    }
    __syncthreads();
#pragma unroll
    for (int qq = 0; qq < QB; qq++)
        mx[qq] = fmaxf(fmaxf(redm[qq][0], redm[qq][1]),
                       fmaxf(redm[qq][2], redm[qq][3]));

    // exp + per-thread sum
    float ls[QB];
#pragma unroll
    for (int qq = 0; qq < QB; qq++) ls[qq] = 0.f;
#pragma unroll
    for (int j = 0; j < 4; j++)
#pragma unroll
        for (int qq = 0; qq < QB; qq++) {
            const float e = __expf(sc[j][qq] - mx[qq]);  // exp(-inf) = 0 for masked
            sc[j][qq] = e;
            ls[qq] += e;
        }

    // wave-level sum reduce, then cross-wave
#pragma unroll
    for (int off = 32; off > 0; off >>= 1)
#pragma unroll
        for (int qq = 0; qq < QB; qq++)
            ls[qq] += __shfl_xor(ls[qq], off);
    if (lane == 0) {
#pragma unroll
        for (int qq = 0; qq < QB; qq++) reds[qq][wid] = ls[qq];
    }
    __syncthreads();

    float inv[QB];
#pragma unroll
    for (int qq = 0; qq < QB; qq++)
        inv[qq] = 1.0f / (reds[qq][0] + reds[qq][1] + reds[qq][2] + reds[qq][3]);

    // write normalized weights (coalesced along k)
    float* wBase = W + ((size_t)(b * Hq + h) * Sq + q0) * Sq;
#pragma unroll
    for (int j = 0; j < 4; j++) {
        const int k = t + 256 * j;
#pragma unroll
        for (int qq = 0; qq < QB; qq++)
            wBase[(size_t)qq * Sq + k] = sc[j][qq] * inv[qq];
    }
}

// ---------------------------------------------------------------------------
// PV: AO[b,q,h*64+d] = sum_k W[b,h,q,k] * V[b,k,h*64+d]
// Batched register-blocked GEMM: per (b,h), C[1024 q][64 d] = W @ V.
// 64x64 tile (full d), BK=16, 256 threads, 4x4 micro-tile (gemm_bt structure).
// ---------------------------------------------------------------------------
__global__ __launch_bounds__(256) void attn_pv(
    const float* __restrict__ W,  // [B,H,S,S]
    const float* __restrict__ V,  // [B*S, E]
    float* __restrict__ AO)       // [B*S, E]
{
    const int bh = blockIdx.y;          // 0..63
    const int h  = bh & (Hq - 1);
    const int b  = bh >> 4;
    const int bm = blockIdx.x * TILE;   // q tile base

    __shared__ float As[BK][APAD];      // W tile: As[kk][q]
    __shared__ float Bs[BK][APAD];      // V tile: Bs[kk][d]

    const float* Wbase = W + (size_t)(b * Hq + h) * Sq * Sq;
    const float* Vbase = V + (size_t)b * Sq * Eq + h * Dq;

    const int t  = threadIdx.x;
    const int tn = t & 15;
    const int tm = t >> 4;
    const int lk = t & 15;
    const int lm = t >> 4;
    const int ld = t & 63;   // d for V loads
    const int lr = t >> 6;   // 0..3

    float acc[4][4] = {};

    for (int k0 = 0; k0 < Sq; k0 += BK) {
#pragma unroll
        for (int r = 0; r < 4; r++)
            As[lk][lm + 16 * r] = Wbase[(size_t)(bm + lm + 16 * r) * Sq + k0 + lk];
#pragma unroll
        for (int r = 0; r < 4; r++) {
            const int kk = lr + 4 * r;
            Bs[kk][ld] = Vbase[(size_t)(k0 + kk) * Eq + ld];
        }
        __syncthreads();
#pragma unroll
        for (int kk = 0; kk < BK; kk++) {
            float a[4], bb[4];
#pragma unroll
            for (int i = 0; i < 4; i++) a[i] = As[kk][tm * 4 + i];
#pragma unroll
            for (int j = 0; j < 4; j++) bb[j] = Bs[kk][tn * 4 + j];
#pragma unroll
            for (int i = 0; i < 4; i++)
#pragma unroll
                for (int j = 0; j < 4; j++)
                    acc[i][j] += a[i] * bb[j];
        }
        __syncthreads();
    }

#pragma unroll
    for (int i = 0; i < 4; i++) {
        float4 o;
        o.x = acc[i][0]; o.y = acc[i][1]; o.z = acc[i][2]; o.w = acc[i][3];
        *(float4*)(AO + (size_t)(b * Sq + bm + tm * 4 + i) * Eq + h * Dq + tn * 4) = o;
    }
}

// ---------------------------------------------------------------------------
extern "C" void kernel_launch(void* const* d_in, const int* in_sizes, int n_in,
                              void* d_out, int out_size, void* d_ws, size_t ws_size,
                              hipStream_t stream) {
    const float* x         = (const float*)d_in[0];
    const float* attn_bias = (const float*)d_in[1];
    const int*   mask      = (const int*)d_in[2];
    const float* Wq = (const float*)d_in[3];
    const float* bq = (const float*)d_in[4];
    const float* Wk = (const float*)d_in[5];
    const float* bk = (const float*)d_in[6];
    const float* Wv = (const float*)d_in[7];
    const float* bv = (const float*)d_in[8];
    const float* Wo = (const float*)d_in[9];
    const float* bo = (const float*)d_in[10];

    float* out    = (float*)d_out;                       // [B,S,E]
    float* attn_w = out + (size_t)Bq * Sq * Eq;          // [B,H,S,S]

    const size_t rows = (size_t)Bq * Sq;                 // 4096
    float* Q  = (float*)d_ws;                            // [4096,1024]
    float* K  = Q + rows * Eq;
    float* V  = K + rows * Eq;
    float* AO = Q;  // reuse Q's slot after scores are done

    const dim3 gemm_grid(Eq / TILE, (int)(rows / TILE)); // 16 x 64
    const float scaling = 0.125f;                        // D^-0.5

    gemm_bt<<<gemm_grid, 256, 0, stream>>>(x, Wq, bq, Q, (int)rows, Eq, Eq, scaling);
    gemm_bt<<<gemm_grid, 256, 0, stream>>>(x, Wk, bk, K, (int)rows, Eq, Eq, 1.0f);
    gemm_bt<<<gemm_grid, 256, 0, stream>>>(x, Wv, bv, V, (int)rows, Eq, Eq, 1.0f);

    attn_scores<<<Bq * Hq * (Sq / QB), 256, 0, stream>>>(Q, K, attn_bias, mask, attn_w);

    const dim3 pv_grid(Sq / TILE, Bq * Hq);              // 16 x 64
    attn_pv<<<pv_grid, 256, 0, stream>>>(attn_w, V, AO);

    gemm_bt<<<gemm_grid, 256, 0, stream>>>(AO, Wo, bo, out, (int)rows, Eq, Eq, 1.0f);
}

// Round 3
// 1632.736 us; speedup vs baseline: 4.1514x; 4.1514x over previous
//
#include <hip/hip_runtime.h>
#include <hip/hip_bf16.h>
#include <math.h>

// Problem constants
#define Bq 4
#define Sq 1024
#define Eq 1024
#define Hq 16
#define Dq 64

// ---------------------------------------------------------------------------
// GEMM: C[M,N] = (A[M,K] @ Bw[N,K]^T + bias[N]) * scale   (torch Linear style)
// 64x64 tile, BK=16, 256 threads, 4x4 register micro-tile. fp32.
// ---------------------------------------------------------------------------
#define TILE 64
#define BK 16
#define APAD 68  // 64 + 4 pad: keeps 16B alignment for b128 reads, kills bank conflicts

__global__ __launch_bounds__(256) void gemm_bt(
    const float* __restrict__ A,    // [M,K]
    const float* __restrict__ Bw,   // [N,K]
    const float* __restrict__ bias, // [N]
    float* __restrict__ C,          // [M,N]
    int M, int N, int K, float scale)
{
    __shared__ float As[BK][APAD];
    __shared__ float Bs[BK][APAD];

    const int bm = blockIdx.y * TILE;
    const int bn = blockIdx.x * TILE;
    const int t  = threadIdx.x;
    const int tn = t & 15;   // 0..15 -> column group
    const int tm = t >> 4;   // 0..15 -> row group

    float acc[4][4] = {};

    const int lk = t & 15;   // k within tile for loads
    const int lm = t >> 4;   // 0..15

    for (int k0 = 0; k0 < K; k0 += BK) {
#pragma unroll
        for (int r = 0; r < 4; r++) {
            As[lk][lm + 16 * r] = A[(size_t)(bm + lm + 16 * r) * K + k0 + lk];
            Bs[lk][lm + 16 * r] = Bw[(size_t)(bn + lm + 16 * r) * K + k0 + lk];
        }
        __syncthreads();
#pragma unroll
        for (int kk = 0; kk < BK; kk++) {
            float a[4], b[4];
#pragma unroll
            for (int i = 0; i < 4; i++) a[i] = As[kk][tm * 4 + i];
#pragma unroll
            for (int j = 0; j < 4; j++) b[j] = Bs[kk][tn * 4 + j];
#pragma unroll
            for (int i = 0; i < 4; i++)
#pragma unroll
                for (int j = 0; j < 4; j++)
                    acc[i][j] += a[i] * b[j];
        }
        __syncthreads();
    }

    const float4 bb = *(const float4*)(bias + bn + tn * 4);
#pragma unroll
    for (int i = 0; i < 4; i++) {
        const int row = bm + tm * 4 + i;
        float4 o;
        o.x = (acc[i][0] + bb.x) * scale;
        o.y = (acc[i][1] + bb.y) * scale;
        o.z = (acc[i][2] + bb.z) * scale;
        o.w = (acc[i][3] + bb.w) * scale;
        *(float4*)(C + (size_t)row * N + bn + tn * 4) = o;
    }
}

// ---------------------------------------------------------------------------
// Scores + softmax: one block per (b,h, 8-q group). 256 threads.
// Thread t owns k-columns {t, t+256, t+512, t+768} for 8 q rows.
// QB=8 keeps per-thread state (sc[4][8]=32 regs) inside the VGPR budget --
// QB=16 spilled sc to scratch (r1: 16 GB L2 spill traffic, r2: 12.8 GB HBM).
// c-loop pinned to no-unroll so the compiler can't inflate live ranges.
// ---------------------------------------------------------------------------
#define QB 8

__global__ __launch_bounds__(256, 2) void attn_scores(
    const float* __restrict__ Q,     // [B*S, E] (pre-scaled)
    const float* __restrict__ Km,    // [B*S, E]
    const float* __restrict__ bias,  // [B,H,S,S]
    const int*   __restrict__ mask,  // [B,S]
    float* __restrict__ W)           // [B,H,S,S]
{
    const int bid = blockIdx.x;
    const int qc = bid & (Sq / QB - 1);       // 0..127
    const int h  = (bid >> 7) & (Hq - 1);
    const int b  = bid >> 11;
    const int q0 = qc * QB;

    __shared__ __align__(16) float qs[QB][Dq];
    __shared__ float redm[QB][4];
    __shared__ float reds[QB][4];

    const int t = threadIdx.x;

    // load 8 q rows (8*64 floats = 128 float4s)
    if (t < 128) {
        const int qq = t >> 4;   // 16 float4 per row
        const int c4 = t & 15;
        ((float4*)qs[qq])[c4] =
            *(const float4*)(Q + ((size_t)(b * Sq + q0 + qq)) * Eq + h * Dq + c4 * 4);
    }
    __syncthreads();

    const float* Kbase = Km + (size_t)b * Sq * Eq + h * Dq;

    float sc[4][QB];
#pragma unroll
    for (int j = 0; j < 4; j++)
#pragma unroll
        for (int qq = 0; qq < QB; qq++) sc[j][qq] = 0.f;

#pragma unroll 1
    for (int c = 0; c < Dq / 4; c++) {
        float4 kv[4];
#pragma unroll
        for (int j = 0; j < 4; j++)
            kv[j] = *(const float4*)(Kbase + (size_t)(t + 256 * j) * Eq + c * 4);
#pragma unroll
        for (int qh = 0; qh < 2; qh++) {
            float4 qr[4];
#pragma unroll
            for (int u = 0; u < 4; u++) qr[u] = ((const float4*)qs[qh * 4 + u])[c];
#pragma unroll
            for (int j = 0; j < 4; j++)
#pragma unroll
                for (int u = 0; u < 4; u++)
                    sc[j][qh * 4 + u] += kv[j].x * qr[u].x + kv[j].y * qr[u].y
                                       + kv[j].z * qr[u].z + kv[j].w * qr[u].w;
        }
    }

    // bias + mask + per-thread max
    const int* mrow = mask + b * Sq;
    const float* biasBase = bias + ((size_t)(b * Hq + h) * Sq + q0) * Sq;

    float mx[QB];
#pragma unroll
    for (int qq = 0; qq < QB; qq++) mx[qq] = -INFINITY;

#pragma unroll
    for (int j = 0; j < 4; j++) {
        const int k = t + 256 * j;
        const bool msk = (mrow[k] != 0);
#pragma unroll
        for (int qq = 0; qq < QB; qq++) {
            float d = msk ? -INFINITY : (sc[j][qq] + biasBase[(size_t)qq * Sq + k]);
            sc[j][qq] = d;
            mx[qq] = fmaxf(mx[qq], d);
        }
    }

    const int lane = t & 63;
    const int wid  = t >> 6;

    // wave-level max reduce, then cross-wave (4 waves)
#pragma unroll
    for (int off = 32; off > 0; off >>= 1)
#pragma unroll
        for (int qq = 0; qq < QB; qq++)
            mx[qq] = fmaxf(mx[qq], __shfl_xor(mx[qq], off));
    if (lane == 0) {
#pragma unroll
        for (int qq = 0; qq < QB; qq++) redm[qq][wid] = mx[qq];
    }
    __syncthreads();
#pragma unroll
    for (int qq = 0; qq < QB; qq++)
        mx[qq] = fmaxf(fmaxf(redm[qq][0], redm[qq][1]),
                       fmaxf(redm[qq][2], redm[qq][3]));

    // exp + per-thread sum
    float ls[QB];
#pragma unroll
    for (int qq = 0; qq < QB; qq++) ls[qq] = 0.f;
#pragma unroll
    for (int j = 0; j < 4; j++)
#pragma unroll
        for (int qq = 0; qq < QB; qq++) {
            const float e = __expf(sc[j][qq] - mx[qq]);  // exp(-inf) = 0 for masked
            sc[j][qq] = e;
            ls[qq] += e;
        }

    // wave-level sum reduce, then cross-wave
#pragma unroll
    for (int off = 32; off > 0; off >>= 1)
#pragma unroll
        for (int qq = 0; qq < QB; qq++)
            ls[qq] += __shfl_xor(ls[qq], off);
    if (lane == 0) {
#pragma unroll
        for (int qq = 0; qq < QB; qq++) reds[qq][wid] = ls[qq];
    }
    __syncthreads();

    float inv[QB];
#pragma unroll
    for (int qq = 0; qq < QB; qq++)
        inv[qq] = 1.0f / (reds[qq][0] + reds[qq][1] + reds[qq][2] + reds[qq][3]);

    // write normalized weights (coalesced along k)
    float* wBase = W + ((size_t)(b * Hq + h) * Sq + q0) * Sq;
#pragma unroll
    for (int j = 0; j < 4; j++) {
        const int k = t + 256 * j;
#pragma unroll
        for (int qq = 0; qq < QB; qq++)
            wBase[(size_t)qq * Sq + k] = sc[j][qq] * inv[qq];
    }
}

// ---------------------------------------------------------------------------
// PV: AO[b,q,h*64+d] = sum_k W[b,h,q,k] * V[b,k,h*64+d]
// Batched register-blocked GEMM: per (b,h), C[1024 q][64 d] = W @ V.
// 64x64 tile (full d), BK=16, 256 threads, 4x4 micro-tile (gemm_bt structure).
// ---------------------------------------------------------------------------
__global__ __launch_bounds__(256) void attn_pv(
    const float* __restrict__ W,  // [B,H,S,S]
    const float* __restrict__ V,  // [B*S, E]
    float* __restrict__ AO)       // [B*S, E]
{
    const int bh = blockIdx.y;          // 0..63
    const int h  = bh & (Hq - 1);
    const int b  = bh >> 4;
    const int bm = blockIdx.x * TILE;   // q tile base

    __shared__ float As[BK][APAD];      // W tile: As[kk][q]
    __shared__ float Bs[BK][APAD];      // V tile: Bs[kk][d]

    const float* Wbase = W + (size_t)(b * Hq + h) * Sq * Sq;
    const float* Vbase = V + (size_t)b * Sq * Eq + h * Dq;

    const int t  = threadIdx.x;
    const int tn = t & 15;
    const int tm = t >> 4;
    const int lk = t & 15;
    const int lm = t >> 4;
    const int ld = t & 63;   // d for V loads
    const int lr = t >> 6;   // 0..3

    float acc[4][4] = {};

    for (int k0 = 0; k0 < Sq; k0 += BK) {
#pragma unroll
        for (int r = 0; r < 4; r++)
            As[lk][lm + 16 * r] = Wbase[(size_t)(bm + lm + 16 * r) * Sq + k0 + lk];
#pragma unroll
        for (int r = 0; r < 4; r++) {
            const int kk = lr + 4 * r;
            Bs[kk][ld] = Vbase[(size_t)(k0 + kk) * Eq + ld];
        }
        __syncthreads();
#pragma unroll
        for (int kk = 0; kk < BK; kk++) {
            float a[4], bb[4];
#pragma unroll
            for (int i = 0; i < 4; i++) a[i] = As[kk][tm * 4 + i];
#pragma unroll
            for (int j = 0; j < 4; j++) bb[j] = Bs[kk][tn * 4 + j];
#pragma unroll
            for (int i = 0; i < 4; i++)
#pragma unroll
                for (int j = 0; j < 4; j++)
                    acc[i][j] += a[i] * bb[j];
        }
        __syncthreads();
    }

#pragma unroll
    for (int i = 0; i < 4; i++) {
        float4 o;
        o.x = acc[i][0]; o.y = acc[i][1]; o.z = acc[i][2]; o.w = acc[i][3];
        *(float4*)(AO + (size_t)(b * Sq + bm + tm * 4 + i) * Eq + h * Dq + tn * 4) = o;
    }
}

// ---------------------------------------------------------------------------
extern "C" void kernel_launch(void* const* d_in, const int* in_sizes, int n_in,
                              void* d_out, int out_size, void* d_ws, size_t ws_size,
                              hipStream_t stream) {
    const float* x         = (const float*)d_in[0];
    const float* attn_bias = (const float*)d_in[1];
    const int*   mask      = (const int*)d_in[2];
    const float* Wq = (const float*)d_in[3];
    const float* bq = (const float*)d_in[4];
    const float* Wk = (const float*)d_in[5];
    const float* bk = (const float*)d_in[6];
    const float* Wv = (const float*)d_in[7];
    const float* bv = (const float*)d_in[8];
    const float* Wo = (const float*)d_in[9];
    const float* bo = (const float*)d_in[10];

    float* out    = (float*)d_out;                       // [B,S,E]
    float* attn_w = out + (size_t)Bq * Sq * Eq;          // [B,H,S,S]

    const size_t rows = (size_t)Bq * Sq;                 // 4096
    float* Q  = (float*)d_ws;                            // [4096,1024]
    float* K  = Q + rows * Eq;
    float* V  = K + rows * Eq;
    float* AO = Q;  // reuse Q's slot after scores are done

    const dim3 gemm_grid(Eq / TILE, (int)(rows / TILE)); // 16 x 64
    const float scaling = 0.125f;                        // D^-0.5

    gemm_bt<<<gemm_grid, 256, 0, stream>>>(x, Wq, bq, Q, (int)rows, Eq, Eq, scaling);
    gemm_bt<<<gemm_grid, 256, 0, stream>>>(x, Wk, bk, K, (int)rows, Eq, Eq, 1.0f);
    gemm_bt<<<gemm_grid, 256, 0, stream>>>(x, Wv, bv, V, (int)rows, Eq, Eq, 1.0f);

    attn_scores<<<Bq * Hq * (Sq / QB), 256, 0, stream>>>(Q, K, attn_bias, mask, attn_w);

    const dim3 pv_grid(Sq / TILE, Bq * Hq);              // 16 x 64
    attn_pv<<<pv_grid, 256, 0, stream>>>(attn_w, V, AO);

    gemm_bt<<<gemm_grid, 256, 0, stream>>>(AO, Wo, bo, out, (int)rows, Eq, Eq, 1.0f);
}

// Round 4
// 1245.935 us; speedup vs baseline: 5.4402x; 1.3105x over previous
//
#include <hip/hip_runtime.h>
#include <hip/hip_bf16.h>
#include <math.h>

// Problem constants
#define Bq 4
#define Sq 1024
#define Eq 1024
#define Hq 16
#define Dq 64

// ---------------------------------------------------------------------------
// GEMM: C[M,N] = (A[M,K] @ Bw[N,K]^T + bias[N]) * scale   (torch Linear style)
// 64x64 tile, BK=16, 256 threads, 4x4 register micro-tile. fp32.
// ---------------------------------------------------------------------------
#define TILE 64
#define BK 16
#define APAD 68  // 64 + 4 pad: keeps 16B alignment for b128 reads, kills bank conflicts

__global__ __launch_bounds__(256) void gemm_bt(
    const float* __restrict__ A,    // [M,K]
    const float* __restrict__ Bw,   // [N,K]
    const float* __restrict__ bias, // [N]
    float* __restrict__ C,          // [M,N]
    int M, int N, int K, float scale)
{
    __shared__ float As[BK][APAD];
    __shared__ float Bs[BK][APAD];

    const int bm = blockIdx.y * TILE;
    const int bn = blockIdx.x * TILE;
    const int t  = threadIdx.x;
    const int tn = t & 15;   // 0..15 -> column group
    const int tm = t >> 4;   // 0..15 -> row group

    float acc[4][4] = {};

    const int lk = t & 15;   // k within tile for loads
    const int lm = t >> 4;   // 0..15

    for (int k0 = 0; k0 < K; k0 += BK) {
#pragma unroll
        for (int r = 0; r < 4; r++) {
            As[lk][lm + 16 * r] = A[(size_t)(bm + lm + 16 * r) * K + k0 + lk];
            Bs[lk][lm + 16 * r] = Bw[(size_t)(bn + lm + 16 * r) * K + k0 + lk];
        }
        __syncthreads();
#pragma unroll
        for (int kk = 0; kk < BK; kk++) {
            float a[4], b[4];
#pragma unroll
            for (int i = 0; i < 4; i++) a[i] = As[kk][tm * 4 + i];
#pragma unroll
            for (int j = 0; j < 4; j++) b[j] = Bs[kk][tn * 4 + j];
#pragma unroll
            for (int i = 0; i < 4; i++)
#pragma unroll
                for (int j = 0; j < 4; j++)
                    acc[i][j] += a[i] * b[j];
        }
        __syncthreads();
    }

    const float4 bb = *(const float4*)(bias + bn + tn * 4);
#pragma unroll
    for (int i = 0; i < 4; i++) {
        const int row = bm + tm * 4 + i;
        float4 o;
        o.x = (acc[i][0] + bb.x) * scale;
        o.y = (acc[i][1] + bb.y) * scale;
        o.z = (acc[i][2] + bb.z) * scale;
        o.w = (acc[i][3] + bb.w) * scale;
        *(float4*)(C + (size_t)row * N + bn + tn * 4) = o;
    }
}

// ---------------------------------------------------------------------------
// Same GEMM, but writes the K projection transposed per head:
// Kt[((b*H + h)*D + d) * S + s] = K_proj[b*S+s][h*D+d] + bias
// so attn_scores can read K with coalesced loads along s.
// ---------------------------------------------------------------------------
__global__ __launch_bounds__(256) void gemm_bt_kt(
    const float* __restrict__ A,    // [M,K]  (x)
    const float* __restrict__ Bw,   // [N,K]  (Wk)
    const float* __restrict__ bias, // [N]
    float* __restrict__ Kt,         // [B*H*D, S]
    int M, int N, int K, float scale)
{
    __shared__ float As[BK][APAD];
    __shared__ float Bs[BK][APAD];

    const int bm = blockIdx.y * TILE;
    const int bn = blockIdx.x * TILE;
    const int t  = threadIdx.x;
    const int tn = t & 15;
    const int tm = t >> 4;

    float acc[4][4] = {};

    const int lk = t & 15;
    const int lm = t >> 4;

    for (int k0 = 0; k0 < K; k0 += BK) {
#pragma unroll
        for (int r = 0; r < 4; r++) {
            As[lk][lm + 16 * r] = A[(size_t)(bm + lm + 16 * r) * K + k0 + lk];
            Bs[lk][lm + 16 * r] = Bw[(size_t)(bn + lm + 16 * r) * K + k0 + lk];
        }
        __syncthreads();
#pragma unroll
        for (int kk = 0; kk < BK; kk++) {
            float a[4], b[4];
#pragma unroll
            for (int i = 0; i < 4; i++) a[i] = As[kk][tm * 4 + i];
#pragma unroll
            for (int j = 0; j < 4; j++) b[j] = Bs[kk][tn * 4 + j];
#pragma unroll
            for (int i = 0; i < 4; i++)
#pragma unroll
                for (int j = 0; j < 4; j++)
                    acc[i][j] += a[i] * b[j];
        }
        __syncthreads();
    }

    // Transposed epilogue. rows bm..bm+63 lie within one batch b (Sq % TILE == 0).
    const int row0 = bm + tm * 4;        // b*Sq + s
    const int b    = row0 >> 10;
    const int s    = row0 & (Sq - 1);    // 4-aligned
#pragma unroll
    for (int j = 0; j < 4; j++) {
        const int col = bn + tn * 4 + j; // h*Dq + d
        const int h = col >> 6;
        const int d = col & (Dq - 1);
        const float bb = bias[col];
        float4 o;
        o.x = (acc[0][j] + bb) * scale;
        o.y = (acc[1][j] + bb) * scale;
        o.z = (acc[2][j] + bb) * scale;
        o.w = (acc[3][j] + bb) * scale;
        *(float4*)(Kt + (size_t)((b * Hq + h) * Dq + d) * Sq + s) = o;
    }
}

// ---------------------------------------------------------------------------
// Scores + softmax: one block per (b,h, 8-q group). 256 threads.
// Thread t owns k-columns {4t..4t+3}: all global accesses (Kt, bias, mask, W)
// are coalesced float4 per lane. K comes from the head-transposed Kt buffer
// (r3's 4KB-lane-stride K reads were 64 txns/wave-load -> L1-txn-bound, 22% VALU).
// QB=8 keeps per-thread state ~60 VGPR (r3-verified no-spill regime).
// ---------------------------------------------------------------------------
#define QB 8

__global__ __launch_bounds__(256, 2) void attn_scores(
    const float* __restrict__ Q,     // [B*S, E] (pre-scaled)
    const float* __restrict__ Kt,    // [B*H*D, S] head-transposed K
    const float* __restrict__ bias,  // [B,H,S,S]
    const int*   __restrict__ mask,  // [B,S]
    float* __restrict__ W)           // [B,H,S,S]
{
    const int bid = blockIdx.x;
    const int qc = bid & (Sq / QB - 1);       // 0..127
    const int h  = (bid >> 7) & (Hq - 1);
    const int b  = bid >> 11;
    const int q0 = qc * QB;

    __shared__ __align__(16) float qs[QB][Dq];
    __shared__ float redm[QB][4];
    __shared__ float reds[QB][4];

    const int t = threadIdx.x;

    // load 8 q rows (8*64 floats = 128 float4s)
    if (t < 128) {
        const int qq = t >> 4;   // 16 float4 per row
        const int c4 = t & 15;
        ((float4*)qs[qq])[c4] =
            *(const float4*)(Q + ((size_t)(b * Sq + q0 + qq)) * Eq + h * Dq + c4 * 4);
    }
    __syncthreads();

    const float* Ktp = Kt + (size_t)(b * Hq + h) * Dq * Sq;

    float sc[4][QB];
#pragma unroll
    for (int j = 0; j < 4; j++)
#pragma unroll
        for (int qq = 0; qq < QB; qq++) sc[j][qq] = 0.f;

#pragma unroll 1
    for (int d = 0; d < Dq; d++) {
        const float4 kt = *(const float4*)(Ktp + (size_t)d * Sq + 4 * t);
#pragma unroll
        for (int qq = 0; qq < QB; qq++) {
            const float qv = qs[qq][d];
            sc[0][qq] += kt.x * qv;
            sc[1][qq] += kt.y * qv;
            sc[2][qq] += kt.z * qv;
            sc[3][qq] += kt.w * qv;
        }
    }

    // bias + mask + per-thread max
    const int*  mrow = mask + b * Sq;
    const int4  mv   = *(const int4*)(mrow + 4 * t);
    const float* biasBase = bias + ((size_t)(b * Hq + h) * Sq + q0) * Sq;

    float mx[QB];
#pragma unroll
    for (int qq = 0; qq < QB; qq++) {
        const float4 bv = *(const float4*)(biasBase + (size_t)qq * Sq + 4 * t);
        float d0 = (mv.x != 0) ? -INFINITY : (sc[0][qq] + bv.x);
        float d1 = (mv.y != 0) ? -INFINITY : (sc[1][qq] + bv.y);
        float d2 = (mv.z != 0) ? -INFINITY : (sc[2][qq] + bv.z);
        float d3 = (mv.w != 0) ? -INFINITY : (sc[3][qq] + bv.w);
        sc[0][qq] = d0; sc[1][qq] = d1; sc[2][qq] = d2; sc[3][qq] = d3;
        mx[qq] = fmaxf(fmaxf(d0, d1), fmaxf(d2, d3));
    }

    const int lane = t & 63;
    const int wid  = t >> 6;

    // wave-level max reduce, then cross-wave (4 waves)
#pragma unroll
    for (int off = 32; off > 0; off >>= 1)
#pragma unroll
        for (int qq = 0; qq < QB; qq++)
            mx[qq] = fmaxf(mx[qq], __shfl_xor(mx[qq], off));
    if (lane == 0) {
#pragma unroll
        for (int qq = 0; qq < QB; qq++) redm[qq][wid] = mx[qq];
    }
    __syncthreads();
#pragma unroll
    for (int qq = 0; qq < QB; qq++)
        mx[qq] = fmaxf(fmaxf(redm[qq][0], redm[qq][1]),
                       fmaxf(redm[qq][2], redm[qq][3]));

    // exp + per-thread sum
    float ls[QB];
#pragma unroll
    for (int qq = 0; qq < QB; qq++) ls[qq] = 0.f;
#pragma unroll
    for (int j = 0; j < 4; j++)
#pragma unroll
        for (int qq = 0; qq < QB; qq++) {
            const float e = __expf(sc[j][qq] - mx[qq]);  // exp(-inf) = 0 for masked
            sc[j][qq] = e;
            ls[qq] += e;
        }

    // wave-level sum reduce, then cross-wave
#pragma unroll
    for (int off = 32; off > 0; off >>= 1)
#pragma unroll
        for (int qq = 0; qq < QB; qq++)
            ls[qq] += __shfl_xor(ls[qq], off);
    if (lane == 0) {
#pragma unroll
        for (int qq = 0; qq < QB; qq++) reds[qq][wid] = ls[qq];
    }
    __syncthreads();

    float inv[QB];
#pragma unroll
    for (int qq = 0; qq < QB; qq++)
        inv[qq] = 1.0f / (reds[qq][0] + reds[qq][1] + reds[qq][2] + reds[qq][3]);

    // write normalized weights (coalesced float4 along k)
    float* wBase = W + ((size_t)(b * Hq + h) * Sq + q0) * Sq;
#pragma unroll
    for (int qq = 0; qq < QB; qq++) {
        float4 o;
        o.x = sc[0][qq] * inv[qq];
        o.y = sc[1][qq] * inv[qq];
        o.z = sc[2][qq] * inv[qq];
        o.w = sc[3][qq] * inv[qq];
        *(float4*)(wBase + (size_t)qq * Sq + 4 * t) = o;
    }
}

// ---------------------------------------------------------------------------
// PV: AO[b,q,h*64+d] = sum_k W[b,h,q,k] * V[b,k,h*64+d]
// Batched register-blocked GEMM: per (b,h), C[1024 q][64 d] = W @ V.
// 64x64 tile (full d), BK=16, 256 threads, 4x4 micro-tile (gemm_bt structure).
// ---------------------------------------------------------------------------
__global__ __launch_bounds__(256) void attn_pv(
    const float* __restrict__ W,  // [B,H,S,S]
    const float* __restrict__ V,  // [B*S, E]
    float* __restrict__ AO)       // [B*S, E]
{
    const int bh = blockIdx.y;          // 0..63
    const int h  = bh & (Hq - 1);
    const int b  = bh >> 4;
    const int bm = blockIdx.x * TILE;   // q tile base

    __shared__ float As[BK][APAD];      // W tile: As[kk][q]
    __shared__ float Bs[BK][APAD];      // V tile: Bs[kk][d]

    const float* Wbase = W + (size_t)(b * Hq + h) * Sq * Sq;
    const float* Vbase = V + (size_t)b * Sq * Eq + h * Dq;

    const int t  = threadIdx.x;
    const int tn = t & 15;
    const int tm = t >> 4;
    const int lk = t & 15;
    const int lm = t >> 4;
    const int ld = t & 63;   // d for V loads
    const int lr = t >> 6;   // 0..3

    float acc[4][4] = {};

    for (int k0 = 0; k0 < Sq; k0 += BK) {
#pragma unroll
        for (int r = 0; r < 4; r++)
            As[lk][lm + 16 * r] = Wbase[(size_t)(bm + lm + 16 * r) * Sq + k0 + lk];
#pragma unroll
        for (int r = 0; r < 4; r++) {
            const int kk = lr + 4 * r;
            Bs[kk][ld] = Vbase[(size_t)(k0 + kk) * Eq + ld];
        }
        __syncthreads();
#pragma unroll
        for (int kk = 0; kk < BK; kk++) {
            float a[4], bb[4];
#pragma unroll
            for (int i = 0; i < 4; i++) a[i] = As[kk][tm * 4 + i];
#pragma unroll
            for (int j = 0; j < 4; j++) bb[j] = Bs[kk][tn * 4 + j];
#pragma unroll
            for (int i = 0; i < 4; i++)
#pragma unroll
                for (int j = 0; j < 4; j++)
                    acc[i][j] += a[i] * bb[j];
        }
        __syncthreads();
    }

#pragma unroll
    for (int i = 0; i < 4; i++) {
        float4 o;
        o.x = acc[i][0]; o.y = acc[i][1]; o.z = acc[i][2]; o.w = acc[i][3];
        *(float4*)(AO + (size_t)(b * Sq + bm + tm * 4 + i) * Eq + h * Dq + tn * 4) = o;
    }
}

// ---------------------------------------------------------------------------
extern "C" void kernel_launch(void* const* d_in, const int* in_sizes, int n_in,
                              void* d_out, int out_size, void* d_ws, size_t ws_size,
                              hipStream_t stream) {
    const float* x         = (const float*)d_in[0];
    const float* attn_bias = (const float*)d_in[1];
    const int*   mask      = (const int*)d_in[2];
    const float* Wq = (const float*)d_in[3];
    const float* bq = (const float*)d_in[4];
    const float* Wk = (const float*)d_in[5];
    const float* bk = (const float*)d_in[6];
    const float* Wv = (const float*)d_in[7];
    const float* bv = (const float*)d_in[8];
    const float* Wo = (const float*)d_in[9];
    const float* bo = (const float*)d_in[10];

    float* out    = (float*)d_out;                       // [B,S,E]
    float* attn_w = out + (size_t)Bq * Sq * Eq;          // [B,H,S,S]

    const size_t rows = (size_t)Bq * Sq;                 // 4096
    float* Q  = (float*)d_ws;                            // [4096,1024]
    float* Kt = Q + rows * Eq;                           // [B*H*D, S] transposed K
    float* V  = Kt + rows * Eq;
    float* AO = Q;  // reuse Q's slot after scores are done

    const dim3 gemm_grid(Eq / TILE, (int)(rows / TILE)); // 16 x 64
    const float scaling = 0.125f;                        // D^-0.5

    gemm_bt<<<gemm_grid, 256, 0, stream>>>(x, Wq, bq, Q, (int)rows, Eq, Eq, scaling);
    gemm_bt_kt<<<gemm_grid, 256, 0, stream>>>(x, Wk, bk, Kt, (int)rows, Eq, Eq, 1.0f);
    gemm_bt<<<gemm_grid, 256, 0, stream>>>(x, Wv, bv, V, (int)rows, Eq, Eq, 1.0f);

    attn_scores<<<Bq * Hq * (Sq / QB), 256, 0, stream>>>(Q, Kt, attn_bias, mask, attn_w);

    const dim3 pv_grid(Sq / TILE, Bq * Hq);              // 16 x 64
    attn_pv<<<pv_grid, 256, 0, stream>>>(attn_w, V, AO);

    gemm_bt<<<gemm_grid, 256, 0, stream>>>(AO, Wo, bo, out, (int)rows, Eq, Eq, 1.0f);
}